// Round 7
// baseline (110.972 us; speedup 1.0000x reference)
//
#include <hip/hip_runtime.h>

// Problem constants (B=4, C=64, H=W=128, O=64, K=3, stride=1, pad=1, dil=1)
#define B_   4
#define C_   64
#define O_   64
#define H_   128
#define W_   128
#define HW_  (H_ * W_)
#define KK_  9
#define M_   18          // 2*KK offset channels

typedef short  short8  __attribute__((ext_vector_type(8)));
typedef float  floatx4 __attribute__((ext_vector_type(4)));
typedef float  float2v __attribute__((ext_vector_type(2)));
typedef unsigned int   uint4v   __attribute__((ext_vector_type(4)));
typedef unsigned short ushort8v __attribute__((ext_vector_type(8)));

static __device__ __forceinline__ unsigned short f2bf(float f) {
    unsigned int u = __float_as_uint(f);
    u += 0x7FFFu + ((u >> 16) & 1u);     // round-to-nearest-even
    return (unsigned short)(u >> 16);
}
// unpack a 32-bit word holding 2 bf16 -> v2f32
static __device__ __forceinline__ float2v bf2x(unsigned int q) {
    float2v r;
    r.x = __uint_as_float(q << 16);
    r.y = __uint_as_float(q & 0xFFFF0000u);
    return r;
}
// guaranteed packed fp32 math (VOP3P)
static __device__ __forceinline__ float2v pk_mul(float2v a, float2v b) {
    float2v d;
    asm("v_pk_mul_f32 %0, %1, %2" : "=v"(d) : "v"(a), "v"(b));
    return d;
}
static __device__ __forceinline__ float2v pk_fma(float2v a, float2v b, float2v c) {
    float2v d;
    asm("v_pk_fma_f32 %0, %1, %2, %3" : "=v"(d) : "v"(a), "v"(b), "v"(c));
    return d;
}

// ---------------------------------------------------------------------------
// Prep (verbatim round-5, verified): x -> grouped xT[b][g4][y][x][c16] bf16,
// plus lane-ordered wtbf / owtbf B-fragments.
// ---------------------------------------------------------------------------
__global__ __launch_bounds__(256) void prep(
        const float* __restrict__ x, const float* __restrict__ w,
        const float* __restrict__ ow, unsigned short* __restrict__ xT,
        unsigned short* __restrict__ wtbf, unsigned short* __restrict__ owtbf) {
    const int blk = blockIdx.x;
    if (blk < 1024) {
        __shared__ unsigned short T[64][70];    // stride 35 words (odd)
        const int tid  = threadIdx.x;
        const int half = blk & 1;
        const int y    = (blk >> 1) & (H_ - 1);
        const int b    = blk >> 8;
        const float* xby = x + (size_t)b * C_ * HW_ + y * W_ + half * 64;
        for (int i = tid; i < 64 * 64; i += 256) {
            const int c = i >> 6, xc = i & 63;
            T[xc][c] = f2bf(xby[(size_t)c * HW_ + xc]);
        }
        __syncthreads();
        for (int j = tid; j < 512; j += 256) {
            const int x8 = j >> 3, c8 = j & 7;
            const int gq  = c8 >> 1;
            const int sub = (c8 & 1) * 8;
            uint4v pk;
            #pragma unroll
            for (int k = 0; k < 4; ++k)
                pk[k] = *(const unsigned int*)&T[x8][c8 * 8 + k * 2];
            unsigned short* dst = xT
                + ((size_t)(b * 4 + gq) * HW_ + y * W_ + half * 64 + x8) * 16
                + sub;
            *(uint4v*)dst = pk;
        }
    } else if (blk < 1042) {
        // wtbf: i = (cks*4 + ot)*64 + lane
        const int i = (blk - 1024) * 256 + threadIdx.x;
        const int lane = i & 63, rest = i >> 6;
        const int ot = rest & 3, cks = rest >> 2;      // cks = tap*2+chalf
        const int chunk = cks / 6, ks = cks % 6;
        const int o = ot * 16 + (lane & 15);
        const int kbase = chunk * 192 + ks * 32 + (lane >> 4) * 8;
        ushort8v pk;
        #pragma unroll
        for (int j = 0; j < 8; ++j) {
            const int k = kbase + j;                   // k = tap*64 + c
            pk[j] = f2bf(w[o * 576 + (k & 63) * 9 + (k >> 6)]);
        }
        *(ushort8v*)&wtbf[(size_t)i * 8] = pk;
    } else {
        // owtbf: i = (tks*2 + tile)*64 + lane
        const int i = (blk - 1042) * 256 + threadIdx.x;
        const int lane = i & 63, rest = i >> 6;
        const int tile = rest & 1, tks = rest >> 1;    // tks = tap*2+ks
        const int tap = tks >> 1, ks = tks & 1;
        const int m = tile * 16 + (lane & 15);
        const int cb = ks * 32 + (lane >> 4) * 8;
        ushort8v pk;
        #pragma unroll
        for (int j = 0; j < 8; ++j)
            pk[j] = (m < M_) ? f2bf(ow[m * 576 + (cb + j) * 9 + tap])
                             : (unsigned short)0;
        *(ushort8v*)&owtbf[(size_t)i * 8] = pk;
    }
}

// ---------------------------------------------------------------------------
// Fused deformable conv, LDS-GATHER version. 512 thr = 8 waves (p = px-tile,
// h = tap parity).
//  Stage: tile[5][68][64ch] bf16 = rows [ho-2,ho+2], px [wo_base-2,wo_base+66),
//    XOR-swizzled per 16B slot (slot = c8 ^ (px&7)) -> px-strided b128 reads
//    hit each bank exactly 8x (= structural minimum). Zero-filled OOB.
//  A2: offset conv via MFMA straight from tile, split over h (18 MFMA each).
//  B:  per tap, geometry; if __all(corners within tile) -> 8x ds_read_b128
//    (120cy LDS vs ~500cy L3: r4 showed gather-latency-bound, all pipes
//    <25% busy); rare fallback = old global-xT path (offset-independent
//    correctness).
//  Merge: 2 phases through 8.7KB union buffer (h1 partial -> h0 add+bias ->
//    cooperative coalesced store).
// LDS 52.2KB -> 3 blocks x 8 waves = 24 waves/CU.
// ---------------------------------------------------------------------------
__global__ __launch_bounds__(512, 6) void dcn_fused(
        const unsigned short* __restrict__ xT,
        const unsigned short* __restrict__ owtbf, const float* __restrict__ ob,
        const unsigned short* __restrict__ wtbf, const float* __restrict__ bias,
        float* __restrict__ out) {
    __shared__ unsigned short tile[5][68][64];   // 43520 B, swizzled
    __shared__ union {
        float offs[4][M_][16];                   // 4608 B (phase A2/B)
        float mrg[2][4][16][17];                 // 8704 B (merge)
    } v;

    const int tid    = threadIdx.x;
    const int lane   = tid & 63;
    const int wsl    = __builtin_amdgcn_readfirstlane(tid >> 6);   // 0..7
    const int p      = wsl & 3;                  // px-tile
    const int h      = wsl >> 2;                 // tap parity
    const int lane15 = lane & 15;
    const int quad   = lane >> 4;

    // XCD-banded remap (g%8 = XCD): XCD x -> rows [16x,16x+16), all b/half
    const int g    = blockIdx.x;
    const int xcd  = g & 7;
    const int slot = g >> 3;
    const int ho   = xcd * 16 + (slot >> 3);
    const int b    = (slot >> 1) & 3;
    const int wo_base = (slot & 1) << 6;

    const unsigned short* xTb = xT + (size_t)b * (4 * HW_ * 16);
    unsigned short* tp = &tile[0][0][0];

    // ---------------- Stage swizzled 5-row tile from xT ---------------------
    // tile[row][px][.] = x[.][ho-2+row][wo_base-2+px]; 16B chunk c8 goes to
    // slot (c8 ^ (px&7)).
    for (int j = tid; j < 5 * 68 * 8; j += 512) {
        const int row = j / (68 * 8);
        const int rem = j - row * (68 * 8);
        const int px = rem >> 3, c8 = rem & 7;
        const int y  = ho - 2 + row;
        const int cx = wo_base - 2 + px;
        ushort8v p0 = {0, 0, 0, 0, 0, 0, 0, 0};
        if ((unsigned)y < (unsigned)H_ && (unsigned)cx < (unsigned)W_) {
            const int gq = c8 >> 1, sub = (c8 & 1) * 8;
            p0 = *(const ushort8v*)&xTb[(size_t)gq * (HW_ * 16)
                                        + ((size_t)y * W_ + cx) * 16 + sub];
        }
        const int sl = c8 ^ (px & 7);
        *(ushort8v*)&tp[(row * 68 + px) * 64 + sl * 8] = p0;
    }
    __syncthreads();

    // ---------------- A2: MFMA offset conv from tile, split over h ----------
    {
        floatx4 oa = (floatx4){0.f, 0.f, 0.f, 0.f};
        #pragma unroll
        for (int ky = 0; ky < 3; ++ky) {
            #pragma unroll
            for (int kx = 0; kx < 3; ++kx) {
                const int tap = ky * 3 + kx;
                #pragma unroll
                for (int ks = 0; ks < 2; ++ks) {
                    const int pxA = p * 16 + lane15 + kx + 1;  // tile px idx
                    const int sA  = (ks * 4 + quad) ^ (pxA & 7);
                    const short8 af = *(const short8*)
                        &tp[((ky + 1) * 68 + pxA) * 64 + sA * 8];
                    const int fb = ((tap * 2 + ks) * 2 + h) * 64 + lane;
                    const short8 bf = *(const short8*)&owtbf[(size_t)fb * 8];
                    oa = __builtin_amdgcn_mfma_f32_16x16x32_bf16(af, bf, oa, 0, 0, 0);
                }
            }
        }
        if (h == 0) {
            const float ob0 = ob[lane15];
            #pragma unroll
            for (int r = 0; r < 4; ++r) oa[r] += ob0;
            *(floatx4*)&v.offs[p][lane15][quad * 4] = oa;
        } else if (lane15 < 2) {
            const float ob1 = ob[16 + lane15];
            #pragma unroll
            for (int r = 0; r < 4; ++r) oa[r] += ob1;
            *(floatx4*)&v.offs[p][16 + lane15][quad * 4] = oa;
        }
    }
    __syncthreads();

    // ---------------- Phase B: LDS gathers (global fallback) ----------------
    const int pxg = p * 16 + lane15;       // px within the 64-px segment
    floatx4 acc[4];
    #pragma unroll
    for (int t = 0; t < 4; ++t) acc[t] = (floatx4){0.f, 0.f, 0.f, 0.f};

    #pragma unroll 2
    for (int k = h; k < 9; k += 2) {       // h0: 0,2,4,6,8; h1: 1,3,5,7
        const int ky = k / 3, kx = k - ky * 3;
        const float offy = v.offs[p][2 * k][lane15];
        const float offx = v.offs[p][2 * k + 1][lane15];
        const float py  = (float)(ho - 1 + ky) + offy;
        const float pxx = (float)(wo_base - 1 + kx + pxg) + offx;
        const float fy = floorf(py), fx = floorf(pxx);
        const int y0 = (int)fy, x0 = (int)fx;
        const int y1 = y0 + 1,  x1 = x0 + 1;
        const float wy1 = py - fy,  wy0 = 1.f - wy1;
        const float wx1 = pxx - fx, wx0 = 1.f - wx1;
        const bool y0v = (unsigned)y0 < (unsigned)H_;
        const bool y1v = (unsigned)y1 < (unsigned)H_;
        const bool x0v = (unsigned)x0 < (unsigned)W_;
        const bool x1v = (unsigned)x1 < (unsigned)W_;
        const float w00 = (y0v && x0v) ? wy0 * wx0 : 0.f;
        const float w01 = (y0v && x1v) ? wy0 * wx1 : 0.f;
        const float w10 = (y1v && x0v) ? wy1 * wx0 : 0.f;
        const float w11 = (y1v && x1v) ? wy1 * wx1 : 0.f;
        const float2v w00_2 = {w00, w00};
        const float2v w01_2 = {w01, w01};
        const float2v w10_2 = {w10, w10};
        const float2v w11_2 = {w11, w11};
        const int ry0 = min(max(y0, 0), H_ - 1);
        const int ry1 = min(max(y1, 0), H_ - 1);
        const int cx0 = min(max(x0, 0), W_ - 1);
        const int cx1 = min(max(x1, 0), W_ - 1);
        // in-tile test on CLAMPED coords (tile = rows [ho-2,ho+2],
        // px [wo_base-2, wo_base+65])
        const bool ok = (ry0 >= ho - 2) && (ry1 <= ho + 2) &&
                        (cx0 >= wo_base - 2) && (cx1 <= wo_base + 65);
        #pragma unroll
        for (int chalf = 0; chalf < 2; ++chalf) {
            const int c8 = chalf * 4 + quad;
            uint4v q00, q01, q10, q11;
            if (__all(ok)) {
                const int r0 = (ry0 - (ho - 2)) * 68;
                const int r1 = (ry1 - (ho - 2)) * 68;
                const int p0 = cx0 - (wo_base - 2);
                const int p1 = cx1 - (wo_base - 2);
                q00 = *(const uint4v*)&tp[(r0 + p0) * 64 + ((c8 ^ (p0 & 7)) * 8)];
                q01 = *(const uint4v*)&tp[(r0 + p1) * 64 + ((c8 ^ (p1 & 7)) * 8)];
                q10 = *(const uint4v*)&tp[(r1 + p0) * 64 + ((c8 ^ (p0 & 7)) * 8)];
                q11 = *(const uint4v*)&tp[(r1 + p1) * 64 + ((c8 ^ (p1 & 7)) * 8)];
            } else {
                const int c0 = chalf * 32 + quad * 8;
                const unsigned short* xp =
                    xTb + (size_t)(c0 >> 4) * (HW_ * 16) + (c0 & 8);
                q00 = *(const uint4v*)&xp[(ry0 * W_ + cx0) * 16];
                q01 = *(const uint4v*)&xp[(ry0 * W_ + cx1) * 16];
                q10 = *(const uint4v*)&xp[(ry1 * W_ + cx0) * 16];
                q11 = *(const uint4v*)&xp[(ry1 * W_ + cx1) * 16];
            }
            uint4v pw;
            #pragma unroll
            for (int j = 0; j < 4; ++j) {
                float2v vv = pk_mul(bf2x(q00[j]), w00_2);
                vv = pk_fma(bf2x(q01[j]), w01_2, vv);
                vv = pk_fma(bf2x(q10[j]), w10_2, vv);
                vv = pk_fma(bf2x(q11[j]), w11_2, vv);
                pw[j] = __builtin_amdgcn_perm(
                    __float_as_uint(vv.y) + 0x8000u,
                    __float_as_uint(vv.x) + 0x8000u,
                    0x07060302u);
            }
            const short8 af = *(const short8*)&pw;
            const int cks = k * 2 + chalf;
            // element ((cks*4+t)*64+lane)*8 = cks*2048 + t*512 + lane*8
            const unsigned short* wb = wtbf + (size_t)cks * 2048 + lane * 8;
            #pragma unroll
            for (int t = 0; t < 4; ++t) {
                const short8 bfrag = *(const short8*)&wb[(size_t)t * 512];
                acc[t] = __builtin_amdgcn_mfma_f32_16x16x32_bf16(
                             af, bfrag, acc[t], 0, 0, 0);
            }
        }
    }
    __syncthreads();   // offs dead -> mrg may be used

    // ---------------- Merge halves + epilogue (2 phases x 2 o-tiles) --------
    // acc[t]: o = t*16+lane15, px16 = quad*4+r.
    #pragma unroll
    for (int ph = 0; ph < 2; ++ph) {
        if (h == 1) {
            #pragma unroll
            for (int tt = 0; tt < 2; ++tt)
                #pragma unroll
                for (int r = 0; r < 4; ++r)
                    v.mrg[tt][p][lane15][quad * 4 + r] = acc[ph * 2 + tt][r];
        }
        __syncthreads();
        if (h == 0) {
            #pragma unroll
            for (int tt = 0; tt < 2; ++tt) {
                const float bs = bias[(ph * 2 + tt) * 16 + lane15];
                #pragma unroll
                for (int r = 0; r < 4; ++r)
                    v.mrg[tt][p][lane15][quad * 4 + r] +=
                        acc[ph * 2 + tt][r] + bs;
            }
        }
        __syncthreads();
        {   // cooperative coalesced store: 512 thr x 16B = 2 o-tiles x 64 px
            const int t2   = tid >> 8;           // 0..1
            const int o16  = (tid >> 4) & 15;
            const int px64 = (tid & 15) * 4;
            const int pp   = px64 >> 4, wi = px64 & 15;
            floatx4 val;
            #pragma unroll
            for (int kq = 0; kq < 4; ++kq)
                val[kq] = v.mrg[t2][pp][o16][wi + kq];
            const int o = (ph * 2 + t2) * 16 + o16;
            *(floatx4*)&out[(size_t)(b * O_ + o) * HW_ + ho * W_ + wo_base + px64]
                = val;
        }
        __syncthreads();
    }
}

// ---------------------------------------------------------------------------
extern "C" void kernel_launch(void* const* d_in, const int* in_sizes, int n_in,
                              void* d_out, int out_size, void* d_ws, size_t ws_size,
                              hipStream_t stream) {
    const float* x    = (const float*)d_in[0];  // [4,64,128,128]
    const float* ow   = (const float*)d_in[1];  // [18,64,3,3]
    const float* ob   = (const float*)d_in[2];  // [18]
    const float* w    = (const float*)d_in[3];  // [64,64,3,3]
    const float* bias = (const float*)d_in[4];  // [64]
    float* out = (float*)d_out;                 // [4,64,128,128]

    unsigned short* wtbf  = (unsigned short*)d_ws;      // 4608 frags  73728 B
    unsigned short* owtbf = wtbf + 4608 * 8;            // 2304 frags  36864 B
    unsigned short* xT    = owtbf + 2304 * 8;           // [4][4][HW][16] 8.39 MB

    prep<<<1051, 256, 0, stream>>>(x, w, ow, xT, wtbf, owtbf);
    dcn_fused<<<B_ * H_ * (W_ / 64), 512, 0, stream>>>(xT, owtbf, ob, wtbf, bias, out);
}